// Round 13
// baseline (500.483 us; speedup 1.0000x reference)
//
#include <hip/hip_runtime.h>
#include <hip/hip_bf16.h>
#include <math.h>

#define BB 8
#define LL 2500
#define LPAD 2560
#define DD 100
#define FF 50
#define FP 64
#define YY 8000
#define KS 9
#define LCH 256
#define NCH 10

typedef __attribute__((ext_vector_type(8))) short short8;
typedef __attribute__((ext_vector_type(4))) float f32x4;
typedef float f32x4u __attribute__((ext_vector_type(4), aligned(4)));

__device__ inline f32x4 mfma_bf16(short8 a, short8 b, f32x4 c) {
    return __builtin_amdgcn_mfma_f32_16x16x32_bf16(a, b, c, 0, 0, 0);
}

__device__ inline unsigned short f2bf(float x) {
    unsigned int u = __builtin_bit_cast(unsigned int, x);
    unsigned int r = u + 0x7fffu + ((u >> 16) & 1u);
    return (unsigned short)(r >> 16);
}

__device__ inline unsigned long long pack4bf(const float* a) {
    return (unsigned long long)f2bf(a[0])
         | ((unsigned long long)f2bf(a[1]) << 16)
         | ((unsigned long long)f2bf(a[2]) << 32)
         | ((unsigned long long)f2bf(a[3]) << 48);
}

__device__ inline float bf2f(unsigned short s) {
    return __builtin_bit_cast(float, (unsigned int)s << 16);
}

__device__ inline float tanhfast(float x) {
    float e = __expf(2.f * x);
    return 1.f - 2.f / (e + 1.f);
}

// ---- prep: weights -> wA[64][9][128] bf16; U_w -> Ub[Y][64] bf16 ----
__global__ void k_prep(const float* __restrict__ cw, unsigned short* __restrict__ wA,
                       const float* __restrict__ Uw, unsigned short* __restrict__ Ub) {
    int i = blockIdx.x * blockDim.x + threadIdx.x;
    if (i < 64 * KS * 128) {
        int f = i / (KS * 128);
        int r = i - f * (KS * 128);
        int kk = r >> 7;
        int d = r & 127;
        float v = (f < FF && d < DD) ? cw[(f * DD + d) * KS + kk] : 0.f;
        wA[i] = f2bf(v);
    }
    if (i < YY * FP) {
        int y = i >> 6, f = i & 63;
        float v = (f < FF) ? Uw[y * FF + f] : 0.f;
        Ub[i] = f2bf(v);
    }
}

// ---- kernel A: embed + conv1d(MFMA) + tanh -> hB[b][2560][64], hT[b][64][2560] bf16 ----
__global__ __launch_bounds__(256) void k_conv(const int* __restrict__ x,
                                              const float* __restrict__ embW,
                                              const unsigned short* __restrict__ wA,
                                              const float* __restrict__ cb,
                                              unsigned short* __restrict__ hB,
                                              unsigned short* __restrict__ hT) {
    __shared__ unsigned short eL[72 * 136];
    __shared__ int sX[72];
    int b = blockIdx.x & 7;
    int t = blockIdx.x >> 3;
    int l0 = t * 64;
    int tid = threadIdx.x;

    if (tid < 72) {
        int gl = l0 - 4 + tid;
        sX[tid] = (gl >= 0 && gl < LL) ? x[b * LL + gl] : -1;
    }
    __syncthreads();
    for (int i = tid; i < 72 * 25; i += 256) {
        int row = i / 25, c = i - row * 25;
        int id = sX[row];
        float4 v = make_float4(0.f, 0.f, 0.f, 0.f);
        if (id >= 0) v = *(const float4*)(embW + (size_t)id * DD + c * 4);
        float a[4] = {v.x, v.y, v.z, v.w};
        *(unsigned long long*)&eL[row * 136 + c * 4] = pack4bf(a);
    }
    for (int i = tid; i < 72 * 9; i += 256) {
        int row = i / 9, c = i - row * 9;
        *(unsigned long long*)&eL[row * 136 + 100 + c * 4] = 0ull;
    }
    __syncthreads();

    int w = tid >> 6, lane = tid & 63, lm = lane & 15, g = lane >> 4;
    f32x4 cacc[4];
#pragma unroll
    for (int mt = 0; mt < 4; ++mt) cacc[mt] = (f32x4){0.f, 0.f, 0.f, 0.f};

    for (int kk = 0; kk < KS; ++kk) {
#pragma unroll
        for (int dc = 0; dc < 4; ++dc) {
            short8 bfrag = *(const short8*)&eL[(w * 16 + lm + kk) * 136 + dc * 32 + g * 8];
#pragma unroll
            for (int mt = 0; mt < 4; ++mt) {
                short8 afrag = *(const short8*)(wA + ((mt * 16 + lm) * KS + kk) * 128 + dc * 32 + g * 8);
                cacc[mt] = mfma_bf16(afrag, bfrag, cacc[mt]);
            }
        }
    }

    int l = l0 + w * 16 + lm;
    unsigned long long packs[4];
#pragma unroll
    for (int mt = 0; mt < 4; ++mt) {
        float vals[4];
#pragma unroll
        for (int j = 0; j < 4; ++j) {
            int f = mt * 16 + g * 4 + j;
            vals[j] = (f < FF) ? tanhfast(cacc[mt][j] + cb[f]) : 0.f;
        }
        packs[mt] = pack4bf(vals);
        *(unsigned long long*)&hB[((size_t)b * LPAD + l) * FP + mt * 16 + g * 4] = packs[mt];
    }
    __syncthreads();
    unsigned short* hTile = eL;
#pragma unroll
    for (int mt = 0; mt < 4; ++mt)
#pragma unroll
        for (int j = 0; j < 4; ++j)
            hTile[(mt * 16 + g * 4 + j) * 72 + w * 16 + lm] =
                (unsigned short)(packs[mt] >> (16 * j));
    __syncthreads();
    {
        int f = tid >> 2, q = tid & 3;
        short8 v0 = *(const short8*)&hTile[f * 72 + q * 16];
        short8 v1 = *(const short8*)&hTile[f * 72 + q * 16 + 8];
        unsigned short* dst = hT + ((size_t)b * FP + f) * LPAD + l0 + q * 16;
        *(short8*)dst = v0;
        *(short8*)(dst + 8) = v1;
    }
}

// ---- kernel B: BARRIER-FREE fused attention; wave owns 16 y, private 8KB sA ----
__global__ __launch_bounds__(256, 4) void k_attn9(const unsigned short* __restrict__ hB,
                                                  const unsigned short* __restrict__ hT,
                                                  const unsigned short* __restrict__ Ub,
                                                  const float* __restrict__ fw,
                                                  const float* __restrict__ fb,
                                                  const float* __restrict__ tgt,
                                                  float* __restrict__ out,
                                                  float* __restrict__ lossAcc) {
    __shared__ unsigned short sAall[4][16 * LCH];  // 4 waves x 8 KB, XOR-swizzled, wave-private

    int b = blockIdx.x & 7;
    int y0 = (blockIdx.x >> 3) * 64;
    int tid = threadIdx.x;
    int w = tid >> 6, lane = tid & 63, lm = lane & 15, g = lane >> 4;
    int ybase = y0 + w * 16;

    const unsigned short* hBb = hB + (size_t)b * LPAD * FP;
    const unsigned short* hTb = hT + (size_t)b * FP * LPAD;
    char* sw = (char*)sAall[w];
    int swz = (lm & 7) << 4;

    short8 uf0 = *(const short8*)(Ub + (size_t)(ybase + lm) * FP + g * 8);
    short8 uf1 = *(const short8*)(Ub + (size_t)(ybase + lm) * FP + 32 + g * 8);

    // ---------------- pass 1: denominator (wave-private, no LDS, no barriers) ----------------
    float ssum = 0.f;
    for (int it = 0; it < 157; ++it) {
        const unsigned short* hrow = hBb + (size_t)(it * 16) * FP;
        short8 a0 = *(const short8*)(hrow + lm * FP + g * 8);
        short8 a1 = *(const short8*)(hrow + lm * FP + 32 + g * 8);
        f32x4 cc = {0.f, 0.f, 0.f, 0.f};
        cc = mfma_bf16(a0, uf0, cc);
        cc = mfma_bf16(a1, uf1, cc);
        int lb = it * 16 + g * 4;
#pragma unroll
        for (int j = 0; j < 4; ++j)
            ssum += (lb + j < LL) ? __expf(cc[j]) : 0.f;
    }
    ssum += __shfl_xor(ssum, 16);
    ssum += __shfl_xor(ssum, 32);
    float inv = 1.f / ssum;          // valid for y = ybase + lm (all g lanes)

    // ---------------- pass 2: single pass, zero barriers ----------------
    f32x4 macc[4];
#pragma unroll
    for (int ft = 0; ft < 4; ++ft) macc[ft] = (f32x4){0.f, 0.f, 0.f, 0.f};

    float* alphaW = out + 64001 + ((size_t)b * YY + ybase) * LL;
    for (int c = 0; c < NCH; ++c) {
        int l0c = c * LCH;
        // S: scores -> normalized alpha bf16 into private sA
#pragma unroll 4
        for (int lt = 0; lt < 16; ++lt) {
            int l0 = l0c + lt * 16;
            const unsigned short* hrow = hBb + (size_t)l0 * FP;
            short8 a0 = *(const short8*)(hrow + lm * FP + g * 8);
            short8 a1 = *(const short8*)(hrow + lm * FP + 32 + g * 8);
            f32x4 cc = {0.f, 0.f, 0.f, 0.f};
            cc = mfma_bf16(a0, uf0, cc);
            cc = mfma_bf16(a1, uf1, cc);
            float av[4];
#pragma unroll
            for (int j = 0; j < 4; ++j)
                av[j] = (l0 + g * 4 + j < LL) ? __expf(cc[j]) * inv : 0.f;
            *(unsigned long long*)&sw[lm * 512 + ((lt * 32 + g * 8) ^ swz)] = pack4bf(av);
        }
        // M: m-MFMA, all wave-local (pa from own sA, B-frags from L2-resident hT)
#pragma unroll
        for (int kc = 0; kc < 8; ++kc) {
            short8 pa = *(const short8*)&sw[lm * 512 + ((kc * 64 + g * 16) ^ swz)];
            const unsigned short* htc = hTb + l0c + kc * 32 + g * 8;
#pragma unroll
            for (int ft = 0; ft < 4; ++ft) {
                short8 bf = *(const short8*)(htc + (size_t)(ft * 16 + lm) * LPAD);
                macc[ft] = mfma_bf16(pa, bf, macc[ft]);
            }
        }
        // D: dump, wave-per-row, 1024 B contiguous per instruction, NT
        bool st = (l0c + lane * 4 < LL);
#pragma unroll
        for (int rr = 0; rr < 16; ++rr) {
            if (st) {
                unsigned long long pv = *(const unsigned long long*)
                    &sw[rr * 512 + ((lane * 8) ^ ((rr & 7) << 4))];
                f32x4 v = {bf2f((unsigned short)pv),
                           bf2f((unsigned short)(pv >> 16)),
                           bf2f((unsigned short)(pv >> 32)),
                           bf2f((unsigned short)(pv >> 48))};
                __builtin_nontemporal_store(v,
                    (f32x4u*)(alphaW + (size_t)rr * LL + l0c + lane * 4));
            }
        }
    }

    // ---------------- epilogue: yhat + BCE (wave-private) ----------------
    float bsum = 0.f;
#pragma unroll
    for (int j = 0; j < 4; ++j) {
        int y = ybase + g * 4 + j;
        float z = 0.f;
#pragma unroll
        for (int ft = 0; ft < 4; ++ft) {
            int f = ft * 16 + lm;
            float fwv = (f < FF) ? fw[(size_t)y * FF + f] : 0.f;
            z += macc[ft][j] * fwv;
        }
        z += __shfl_xor(z, 1);
        z += __shfl_xor(z, 2);
        z += __shfl_xor(z, 4);
        z += __shfl_xor(z, 8);
        if (lm == 0) {
            z += fb[y];
            out[b * YY + y] = z;
            float tg = tgt[b * YY + y];
            bsum += fmaxf(z, 0.f) - z * tg + log1pf(__expf(-fabsf(z)));
        }
    }
    bsum += __shfl_xor(bsum, 16);
    bsum += __shfl_xor(bsum, 32);
    if (lane == 0) atomicAdd(lossAcc, bsum);
}

// ---- kernel C: finalize loss ----
__global__ void k_loss(const float* __restrict__ acc, float* __restrict__ out) {
    out[64000] = acc[0] / (float)(BB * YY);
}

extern "C" void kernel_launch(void* const* d_in, const int* in_sizes, int n_in,
                              void* d_out, int out_size, void* d_ws, size_t ws_size,
                              hipStream_t stream) {
    const int*   x    = (const int*)d_in[0];
    const float* tgt  = (const float*)d_in[1];
    const float* embW = (const float*)d_in[2];
    const float* cw   = (const float*)d_in[3];
    const float* cb   = (const float*)d_in[4];
    const float* Uw   = (const float*)d_in[5];
    const float* fw   = (const float*)d_in[6];
    const float* fb   = (const float*)d_in[7];
    float* out = (float*)d_out;

    float*          lossAcc = (float*)d_ws;
    unsigned short* wA = (unsigned short*)((char*)d_ws + 256);
    unsigned short* Ub = (unsigned short*)((char*)d_ws + 163840);
    unsigned short* hB = (unsigned short*)((char*)d_ws + 1212416);
    unsigned short* hT = (unsigned short*)((char*)d_ws + 3833856);

    hipMemsetAsync(d_ws, 0, 4, stream);
    k_prep<<<(YY * FP + 255) / 256, 256, 0, stream>>>(cw, wA, Uw, Ub);
    k_conv<<<BB * 40, 256, 0, stream>>>(x, embW, wA, cb, hB, hT);
    k_attn9<<<125 * 8, 256, 0, stream>>>(hB, hT, Ub, fw, fb, tgt, out, lossAcc);
    k_loss<<<1, 1, 0, stream>>>(lossAcc, out);
}